// Round 1
// baseline (169.651 us; speedup 1.0000x reference)
//
#include <hip/hip_runtime.h>
#include <hip/hip_fp16.h>

// GCN 2-layer forward: out = softmax( A_norm @ relu(A_norm @ (x@W1) + b1) @ W2 + b2 )
// A_norm = D^-1/2 (A + I) D^-1/2, edges are col->row (row = target).
//
// R13 -> R14: SPLIT SCALE FROM GEMM. The x@W1 MFMA has no edge dependency;
// it only needed dinv for the pre-scale. Now: fused dispatch 2 = 391 bin
// blocks + 391 gemm blocks writing UNSCALED fp32 h to hf32 (gemm hides under
// bin's atomics/scan on otherwise-idle CUs; k_bin alone was 1.5 blocks/CU).
// Dispatch 3 (k_sortscale) = CSR sort + hp = fp16(dinv*hf32) rescale —
// numerically identical to the old fused path (same fp32 value, one rounding).
// Also: sortscale's 256-wide Hillis-Steele scan (16 barriers) -> wave0
// shuffle scan (1 barrier). agg1/agg2 untouched.
// 5 dispatches: memset(relcur) -> bin+gemm -> sortscale -> agg1 -> agg2.

typedef _Float16 f16x8 __attribute__((ext_vector_type(8)));
typedef float f32x4 __attribute__((ext_vector_type(4)));

#define CAPSH 12
#define CAP (1 << CAPSH)          // per-bucket pairbuf/scol capacity
#define NBK 784                   // LDS array size (>= nb = 782)

// ---- 1. fused: bin edges into per-bucket slices  |  gemm hf32 = x@W1 -------
// blocks [0, nTileB): bin role (4096-edge tiles, as R13's k_bin).
// blocks [nTileB, nTileB+nGemm): gemm role, 256 nodes/block, fp32 out.
__global__ __launch_bounds__(256, 4) void k_binfused(const int* __restrict__ row,
                                                     const int* __restrict__ col,
                                                     int* __restrict__ relcur,
                                                     unsigned* __restrict__ pairbuf,
                                                     __half* __restrict__ hp,
                                                     const float* __restrict__ x,
                                                     const float* __restrict__ W1,
                                                     float* __restrict__ hf32,
                                                     int E, int nb, int N, int nTileB) {
    __shared__ unsigned items[4096];        // (r&127)<<24 | col
    __shared__ unsigned short bktid[4096];
    __shared__ int cnt[NBK];
    __shared__ int start0[NBK];
    __shared__ int cursor[NBK];
    __shared__ int gbase[NBK];

    int tid = threadIdx.x;

    if (blockIdx.x < nTileB) {
        // ------------------------- bin role -------------------------
        int base = blockIdx.x * 4096;
        int m = E - base; if (m > 4096) m = 4096;

        for (int t = tid; t < nb; t += 256) cnt[t] = 0;
        __syncthreads();
        for (int i = tid; i < m; i += 256) atomicAdd(&cnt[row[base + i] >> 7], 1);
        __syncthreads();
        // wave0: exclusive scan of tile counts -> start0, cursor (13 chunks of 64)
        if (tid < 64) {
            int lane = tid, running = 0;
            for (int ch = 0; ch < 13; ++ch) {
                int idx = ch * 64 + lane;
                int v = (idx < nb) ? cnt[idx] : 0;
                int s = v;
#pragma unroll
                for (int off = 1; off < 64; off <<= 1) {
                    int t = __shfl_up(s, off, 64);
                    if (lane >= off) s += t;
                }
                if (idx < nb) { start0[idx] = running + s - v; cursor[idx] = running + s - v; }
                running += __shfl(s, 63, 64);
            }
        }
        __syncthreads();
        for (int i = tid; i < m; i += 256) {
            int r = row[base + i];
            int c = col[base + i];
            int b = r >> 7;
            int pos = atomicAdd(&cursor[b], 1);
            items[pos] = ((unsigned)(r & 127) << 24) | (unsigned)c;
            bktid[pos] = (unsigned short)b;
        }
        __syncthreads();
        // claim global space: bucket b's slice starts at b*CAP
        for (int t = tid; t < nb; t += 256) {
            int cv = cnt[t];
            if (cv > 0) gbase[t] = (t << CAPSH) + atomicAdd(&relcur[t], cv);
        }
        __syncthreads();
        for (int i = tid; i < m; i += 256) {
            int b = bktid[i];
            pairbuf[gbase[b] + (i - start0[b])] = items[i];
        }
        if (blockIdx.x == 0 && tid < 32) ((int*)(hp + (size_t)N * 64))[tid] = 0;  // zero row
    } else {
        // ------------------------- gemm role ------------------------
        int g = blockIdx.x - nTileB;
        int n0 = g << 8;                       // 256 nodes per gemm block
        int lane = tid & 63, q = lane >> 4, mm = lane & 15;
        // B-frags (W1 fp16): B[k][n], n=nt*16+mm, k=kk*32+q*8+j
        f16x8 bf[4][2];
#pragma unroll
        for (int nt = 0; nt < 4; ++nt)
#pragma unroll
            for (int kk = 0; kk < 2; ++kk)
#pragma unroll
                for (int j = 0; j < 8; ++j)
                    bf[nt][kk][j] = (_Float16)W1[(kk * 32 + q * 8 + j) * 64 + nt * 16 + mm];

        int nn = N - n0; if (nn > 256) nn = 256;   // N%16==0 -> whole tiles
        for (int t = (tid >> 6); t < (nn >> 4); t += 4) {
            const float* xrow = x + (size_t)(n0 + t * 16 + mm) * 64;
            float4 u0 = *(const float4*)(xrow + q * 8);
            float4 u1 = *(const float4*)(xrow + q * 8 + 4);
            float4 u2 = *(const float4*)(xrow + 32 + q * 8);
            float4 u3 = *(const float4*)(xrow + 32 + q * 8 + 4);
            f16x8 a0, a1;
            a0[0] = (_Float16)u0.x; a0[1] = (_Float16)u0.y; a0[2] = (_Float16)u0.z; a0[3] = (_Float16)u0.w;
            a0[4] = (_Float16)u1.x; a0[5] = (_Float16)u1.y; a0[6] = (_Float16)u1.z; a0[7] = (_Float16)u1.w;
            a1[0] = (_Float16)u2.x; a1[1] = (_Float16)u2.y; a1[2] = (_Float16)u2.z; a1[3] = (_Float16)u2.w;
            a1[4] = (_Float16)u3.x; a1[5] = (_Float16)u3.y; a1[6] = (_Float16)u3.z; a1[7] = (_Float16)u3.w;
            f32x4 ac0 = {0.f, 0.f, 0.f, 0.f}, ac1 = ac0, ac2 = ac0, ac3 = ac0;
            ac0 = __builtin_amdgcn_mfma_f32_16x16x32_f16(a0, bf[0][0], ac0, 0, 0, 0);
            ac1 = __builtin_amdgcn_mfma_f32_16x16x32_f16(a0, bf[1][0], ac1, 0, 0, 0);
            ac2 = __builtin_amdgcn_mfma_f32_16x16x32_f16(a0, bf[2][0], ac2, 0, 0, 0);
            ac3 = __builtin_amdgcn_mfma_f32_16x16x32_f16(a0, bf[3][0], ac3, 0, 0, 0);
            ac0 = __builtin_amdgcn_mfma_f32_16x16x32_f16(a1, bf[0][1], ac0, 0, 0, 0);
            ac1 = __builtin_amdgcn_mfma_f32_16x16x32_f16(a1, bf[1][1], ac1, 0, 0, 0);
            ac2 = __builtin_amdgcn_mfma_f32_16x16x32_f16(a1, bf[2][1], ac2, 0, 0, 0);
            ac3 = __builtin_amdgcn_mfma_f32_16x16x32_f16(a1, bf[3][1], ac3, 0, 0, 0);
#pragma unroll
            for (int reg = 0; reg < 4; ++reg) {
                int rl = t * 16 + q * 4 + reg;
                float* dst = hf32 + (size_t)(n0 + rl) * 64 + mm;
                dst[0]  = ac0[reg];
                dst[16] = ac1[reg];
                dst[32] = ac2[reg];
                dst[48] = ac3[reg];
            }
        }
    }
}

// ---- 2. per-bucket counting sort + hp rescale ------------------------------
// One block per bucket (128 nodes): sort its edges -> scol/offsets/deg/dinv,
// then hp[n] = fp16(dinv[n] * hf32[n]) (identical rounding to the old fused
// gemm epilogue). Wave0 shuffle scan replaces the 16-barrier Hillis-Steele.
__global__ __launch_bounds__(256, 4) void k_sortscale(const unsigned* __restrict__ pairbuf,
                                                      const int* __restrict__ relcur,
                                                      const float* __restrict__ hf32,
                                                      int* __restrict__ scol,
                                                      int* __restrict__ offsets,
                                                      int* __restrict__ deg,
                                                      float* __restrict__ dinv,
                                                      __half* __restrict__ hp,
                                                      int N, int nb) {
    __shared__ int cnt[256];      // [128..255] stay 0
    __shared__ int spre[128];     // exclusive prefix
    __shared__ int cur[128];
    __shared__ float sdinv[128];
    int b = blockIdx.x;
    int tid = threadIdx.x;
    int lo = b << CAPSH;
    int hi = lo + relcur[b];
    cnt[tid] = 0;
    __syncthreads();
    for (int i = lo + tid; i < hi; i += 256)
        atomicAdd(&cnt[pairbuf[i] >> 24], 1);      // values in [0,128)
    __syncthreads();
    // wave0: exclusive scan of 128 counts (2 chunks of 64, 1 barrier total)
    if (tid < 64) {
        int lane = tid, running = 0;
#pragma unroll
        for (int ch = 0; ch < 2; ++ch) {
            int idx = ch * 64 + lane;
            int v = cnt[idx];
            int s = v;
#pragma unroll
            for (int off = 1; off < 64; off <<= 1) {
                int t = __shfl_up(s, off, 64);
                if (lane >= off) s += t;
            }
            spre[idx] = running + s - v;
            running += __shfl(s, 63, 64);
        }
    }
    __syncthreads();
    int n0 = b << 7;
    if (tid < 128) {
        int cv = cnt[tid];
        int excl = spre[tid];
        int n = n0 + tid;
        float dv = rsqrtf((float)(cv + 1));        // +1 self-loop
        if (n < N) { offsets[n] = lo + excl; deg[n] = cv; dinv[n] = dv; }
        sdinv[tid] = dv;
        cur[tid] = lo + excl;
    }
    if (b == 0 && tid == 0) {
        offsets[N] = 0; deg[N] = 0;                // clamped-node entry
        scol[nb << CAPSH] = N;                     // sentinel -> zero row
    }
    __syncthreads();
    for (int i = lo + tid; i < hi; i += 256) {
        unsigned it = pairbuf[i];
        int pos = atomicAdd(&cur[it >> 24], 1);
        scol[pos] = (int)(it & 0xFFFFFFu);
    }
    // rescale phase (independent of the scatter above; overlaps with it).
    // 2 threads per row: thread handles 32 floats -> 32 halves (4x 16B stores).
    int rowi = tid >> 1, half = tid & 1;
    int n = n0 + rowi;
    if (n < N) {
        float dv = sdinv[rowi];
        const float4* src = (const float4*)(hf32 + (size_t)n * 64 + half * 32);
        f16x8* dst = (f16x8*)(hp + (size_t)n * 64 + half * 32);
#pragma unroll
        for (int k = 0; k < 4; ++k) {
            float4 u0 = src[2 * k];
            float4 u1 = src[2 * k + 1];
            f16x8 o;
            o[0] = (_Float16)(dv * u0.x); o[1] = (_Float16)(dv * u0.y);
            o[2] = (_Float16)(dv * u0.z); o[3] = (_Float16)(dv * u0.w);
            o[4] = (_Float16)(dv * u1.x); o[5] = (_Float16)(dv * u1.y);
            o[6] = (_Float16)(dv * u1.z); o[7] = (_Float16)(dv * u1.w);
            dst[k] = o;
        }
    }
}

// ---- 3. layer-1 agg + relu(+b1) + 64->2 projection, fused (R10 form) -------
// Wave = 8 nodes; slot=lane>>3 owns a node, chunk=lane&7 owns 16B of its row.
// 8-deep unrolled gathers (8 scol loads + 8 row gathers in flight per slot).
__global__ __launch_bounds__(256, 4) void k_agg1(const __half* __restrict__ hp,
                                                 const int* __restrict__ offsets,
                                                 const int* __restrict__ deg,
                                                 const int* __restrict__ scol,
                                                 const float* __restrict__ dinv,
                                                 const float* __restrict__ b1,
                                                 const float* __restrict__ W2,
                                                 float2* __restrict__ h2p,
                                                 int N, int SENT) {
    int lane = threadIdx.x & 63;
    int slot = lane >> 3;
    int chunk = lane & 7;
    int wid = (int)((blockIdx.x * 256 + threadIdx.x) >> 6);
    int n = wid * 8 + slot;
    int nc = (n < N) ? n : N;                 // row N of hp is the zero row
    int start = offsets[nc];
    int dg = deg[nc];                         // deg[N] = 0
    int maxd = dg;
#pragma unroll
    for (int s = 8; s <= 32; s <<= 1) {
        int o = __shfl_xor(maxd, s, 64);
        maxd = (o > maxd) ? o : maxd;
    }
    const float4* hp4 = (const float4*)hp;    // row stride = 8 float4
    float4 sr = hp4[(size_t)nc * 8 + chunk];  // self term
    __half2 acc0 = ((const __half2*)&sr)[0];
    __half2 acc1 = ((const __half2*)&sr)[1];
    __half2 acc2 = ((const __half2*)&sr)[2];
    __half2 acc3 = ((const __half2*)&sr)[3];
    for (int j0 = 0; j0 < maxd; j0 += 8) {
        int c[8];
#pragma unroll
        for (int u = 0; u < 8; ++u)
            c[u] = scol[(j0 + u < dg) ? (start + j0 + u) : SENT];  // SENT -> N
        float4 r[8];
#pragma unroll
        for (int u = 0; u < 8; ++u) r[u] = hp4[(size_t)c[u] * 8 + chunk];
#pragma unroll
        for (int u = 0; u < 8; ++u) {
            const __half2* hh = (const __half2*)&r[u];
            acc0 = __hadd2(acc0, hh[0]); acc1 = __hadd2(acc1, hh[1]);
            acc2 = __hadd2(acc2, hh[2]); acc3 = __hadd2(acc3, hh[3]);
        }
    }
    float af[8];
    { float2 f;
      f = __half22float2(acc0); af[0] = f.x; af[1] = f.y;
      f = __half22float2(acc1); af[2] = f.x; af[3] = f.y;
      f = __half22float2(acc2); af[4] = f.x; af[5] = f.y;
      f = __half22float2(acc3); af[6] = f.x; af[7] = f.y; }
    float dn = dinv[(n < N) ? n : (N - 1)];
    float4 b1a = ((const float4*)b1)[chunk * 2];
    float4 b1b = ((const float4*)b1)[chunk * 2 + 1];
    float h1[8];
    h1[0] = fmaxf(fmaf(dn, af[0], b1a.x), 0.f);
    h1[1] = fmaxf(fmaf(dn, af[1], b1a.y), 0.f);
    h1[2] = fmaxf(fmaf(dn, af[2], b1a.z), 0.f);
    h1[3] = fmaxf(fmaf(dn, af[3], b1a.w), 0.f);
    h1[4] = fmaxf(fmaf(dn, af[4], b1b.x), 0.f);
    h1[5] = fmaxf(fmaf(dn, af[5], b1b.y), 0.f);
    h1[6] = fmaxf(fmaf(dn, af[6], b1b.z), 0.f);
    h1[7] = fmaxf(fmaf(dn, af[7], b1b.w), 0.f);
    float p0 = 0.f, p1 = 0.f;
#pragma unroll
    for (int k = 0; k < 4; ++k) {   // float4 = W2 rows {8c+2k, 8c+2k+1}
        float4 w = ((const float4*)W2)[chunk * 4 + k];
        p0 = fmaf(h1[2 * k], w.x, p0); p1 = fmaf(h1[2 * k], w.y, p1);
        p0 = fmaf(h1[2 * k + 1], w.z, p0); p1 = fmaf(h1[2 * k + 1], w.w, p1);
    }
#pragma unroll
    for (int s = 1; s <= 4; s <<= 1) {  // reduce across chunk (bits 0,1,2)
        p0 += __shfl_xor(p0, s, 64);
        p1 += __shfl_xor(p1, s, 64);
    }
    if (chunk == 0 && n < N) h2p[n] = make_float2(dn * p0, dn * p1);  // pre-scaled
}

// ---- 4. layer-2 agg + softmax: 16 lanes per node ---------------------------
__global__ __launch_bounds__(256) void k_agg2(const float2* __restrict__ h2p,
                                              const int* __restrict__ offsets,
                                              const int* __restrict__ deg,
                                              const int* __restrict__ scol,
                                              const float* __restrict__ dinv,
                                              const float* __restrict__ b2,
                                              float2* __restrict__ out, int N) {
    int gtid = blockIdx.x * 256 + threadIdx.x;
    int n = gtid >> 4;
    int sub = threadIdx.x & 15;
    if (n >= N) return;
    int start = offsets[n], end = start + deg[n];
    float ax = 0.f, ay = 0.f;
    if (sub == 0) { float2 s = h2p[n]; ax = s.x; ay = s.y; }   // self (pre-scaled)
    for (int j = start + sub; j < end; j += 16) {
        float2 v = h2p[scol[j]];
        ax += v.x; ay += v.y;
    }
#pragma unroll
    for (int s = 1; s <= 8; s <<= 1) {
        ax += __shfl_xor(ax, s, 64);
        ay += __shfl_xor(ay, s, 64);
    }
    if (sub == 0) {
        float dn = dinv[n];
        float l0 = fmaf(dn, ax, b2[0]), l1 = fmaf(dn, ay, b2[1]);
        float m = fmaxf(l0, l1);
        float e0 = __expf(l0 - m), e1 = __expf(l1 - m);
        float inv = 1.0f / (e0 + e1);
        out[n] = make_float2(e0 * inv, e1 * inv);
    }
}

extern "C" void kernel_launch(void* const* d_in, const int* in_sizes, int n_in,
                              void* d_out, int out_size, void* d_ws, size_t ws_size,
                              hipStream_t stream) {
    const float* x  = (const float*)d_in[0];
    const int*   ei = (const int*)d_in[1];
    const float* W1 = (const float*)d_in[2];
    const float* b1 = (const float*)d_in[3];
    const float* W2 = (const float*)d_in[4];
    const float* b2 = (const float*)d_in[5];
    float2* out = (float2*)d_out;

    const int N = in_sizes[0] / 64;     // 100000 (N%16==0, N<2^24)
    const int E = in_sizes[1] / 2;      // 1600000
    const int nb = (N + 127) >> 7;      // 782 buckets of 128 nodes
    const int SENT = nb << CAPSH;
    const int* row = ei;
    const int* col = ei + E;

    char* p = (char*)d_ws;
    auto alloc = [&](size_t bytes) -> void* {
        void* r = (void*)p;
        p += (bytes + 255) & ~(size_t)255;
        return r;
    };
    int*   relcur  = (int*)alloc((size_t)nb * 4);               // memset exact (R4 lesson)
    int*   offsets = (int*)alloc((size_t)(N + 1) * 4);
    int*   deg     = (int*)alloc((size_t)(N + 1) * 4);
    float* dinv    = (float*)alloc((size_t)N * 4);
    unsigned* pairbuf = (unsigned*)alloc((size_t)nb * CAP * 4);
    int*   scol    = (int*)alloc(((size_t)nb * CAP + 1) * 4);   // +1 sentinel
    __half* hp     = (__half*)alloc((size_t)(N + 1) * 64 * 2);  // +1 zero row
    float2* h2p    = (float2*)alloc((size_t)N * 8);
    float* hf32    = (float*)alloc((size_t)N * 64 * 4);         // unscaled x@W1 (fp32)

    const int nTileB = (E + 4095) / 4096;   // 391 bin blocks
    const int nGemm  = (N + 255) >> 8;      // 391 gemm blocks (256 nodes each)

    hipMemsetAsync(relcur, 0, (size_t)nb * 4, stream);
    k_binfused<<<nTileB + nGemm, 256, 0, stream>>>(row, col, relcur, pairbuf, hp,
                                                   x, W1, hf32, E, nb, N, nTileB);
    k_sortscale<<<nb, 256, 0, stream>>>(pairbuf, relcur, hf32, scol, offsets, deg, dinv, hp, N, nb);
    const int nwaves = (N + 7) / 8;                  // 8 nodes per wave
    k_agg1<<<(nwaves + 3) / 4, 256, 0, stream>>>(hp, offsets, deg, scol, dinv, b1, W2, h2p, N, SENT);
    k_agg2<<<(N * 16 + 255) / 256, 256, 0, stream>>>(h2p, offsets, deg, scol, dinv, b2, out, N);
}

// Round 2
// 165.759 us; speedup vs baseline: 1.0235x; 1.0235x over previous
//
#include <hip/hip_runtime.h>
#include <hip/hip_fp16.h>

// GCN 2-layer forward: out = softmax( A_norm @ relu(A_norm @ (x@W1) + b1) @ W2 + b2 )
// A_norm = D^-1/2 (A + I) D^-1/2, edges are col->row (row = target).
//
// R14 -> R15: SCALE AT GATHER, NOT AT STORE. R14's hf32 fp32 round-trip
// (+51MB HBM ~ +8us) cancelled the bin||gemm overlap gain (~5us). Now the
// overlapped gemm writes UNSCALED fp16 hp directly (traffic == R13), the
// sort kernel is a pure CSR build (no gemm, no rescale), and k_agg1 applies
// dinv[c] per gathered row with fp32 accumulation (VALU +2.6us chip-wide,
// hidden under gather latency; numerics strictly better than fp16 accum).
// dinv has N+1 entries with dinv[N]=0 so the sentinel row is 0*0, never NaN.
// 5 dispatches: memset(relcur) -> bin+gemm -> sort -> agg1 -> agg2.

typedef _Float16 f16x8 __attribute__((ext_vector_type(8)));
typedef float f32x4 __attribute__((ext_vector_type(4)));

#define CAPSH 12
#define CAP (1 << CAPSH)          // per-bucket pairbuf/scol capacity
#define NBK 784                   // LDS array size (>= nb = 782)

// ---- 1. fused: bin edges into per-bucket slices  |  gemm hp = fp16(x@W1) ---
// blocks [0, nTileB): bin role (4096-edge tiles).
// blocks [nTileB, nTileB+nGemm): gemm role, 256 nodes/block, unscaled fp16 out.
__global__ __launch_bounds__(256, 4) void k_binfused(const int* __restrict__ row,
                                                     const int* __restrict__ col,
                                                     int* __restrict__ relcur,
                                                     unsigned* __restrict__ pairbuf,
                                                     __half* __restrict__ hp,
                                                     const float* __restrict__ x,
                                                     const float* __restrict__ W1,
                                                     int E, int nb, int N, int nTileB) {
    __shared__ unsigned items[4096];        // (r&127)<<24 | col
    __shared__ unsigned short bktid[4096];
    __shared__ int cnt[NBK];
    __shared__ int start0[NBK];
    __shared__ int cursor[NBK];
    __shared__ int gbase[NBK];

    int tid = threadIdx.x;

    if (blockIdx.x < nTileB) {
        // ------------------------- bin role -------------------------
        int base = blockIdx.x * 4096;
        int m = E - base; if (m > 4096) m = 4096;

        for (int t = tid; t < nb; t += 256) cnt[t] = 0;
        __syncthreads();
        for (int i = tid; i < m; i += 256) atomicAdd(&cnt[row[base + i] >> 7], 1);
        __syncthreads();
        // wave0: exclusive scan of tile counts -> start0, cursor (13 chunks of 64)
        if (tid < 64) {
            int lane = tid, running = 0;
            for (int ch = 0; ch < 13; ++ch) {
                int idx = ch * 64 + lane;
                int v = (idx < nb) ? cnt[idx] : 0;
                int s = v;
#pragma unroll
                for (int off = 1; off < 64; off <<= 1) {
                    int t = __shfl_up(s, off, 64);
                    if (lane >= off) s += t;
                }
                if (idx < nb) { start0[idx] = running + s - v; cursor[idx] = running + s - v; }
                running += __shfl(s, 63, 64);
            }
        }
        __syncthreads();
        for (int i = tid; i < m; i += 256) {
            int r = row[base + i];
            int c = col[base + i];
            int b = r >> 7;
            int pos = atomicAdd(&cursor[b], 1);
            items[pos] = ((unsigned)(r & 127) << 24) | (unsigned)c;
            bktid[pos] = (unsigned short)b;
        }
        __syncthreads();
        // claim global space: bucket b's slice starts at b*CAP
        for (int t = tid; t < nb; t += 256) {
            int cv = cnt[t];
            if (cv > 0) gbase[t] = (t << CAPSH) + atomicAdd(&relcur[t], cv);
        }
        __syncthreads();
        for (int i = tid; i < m; i += 256) {
            int b = bktid[i];
            pairbuf[gbase[b] + (i - start0[b])] = items[i];
        }
        if (blockIdx.x == 0 && tid < 32) ((int*)(hp + (size_t)N * 64))[tid] = 0;  // zero row
    } else {
        // ------------------------- gemm role ------------------------
        int g = blockIdx.x - nTileB;
        int n0 = g << 8;                       // 256 nodes per gemm block
        int lane = tid & 63, q = lane >> 4, mm = lane & 15;
        // B-frags (W1 fp16): B[k][n], n=nt*16+mm, k=kk*32+q*8+j
        f16x8 bf[4][2];
#pragma unroll
        for (int nt = 0; nt < 4; ++nt)
#pragma unroll
            for (int kk = 0; kk < 2; ++kk)
#pragma unroll
                for (int j = 0; j < 8; ++j)
                    bf[nt][kk][j] = (_Float16)W1[(kk * 32 + q * 8 + j) * 64 + nt * 16 + mm];

        int nn = N - n0; if (nn > 256) nn = 256;   // N%16==0 -> whole tiles
        for (int t = (tid >> 6); t < (nn >> 4); t += 4) {
            const float* xrow = x + (size_t)(n0 + t * 16 + mm) * 64;
            float4 u0 = *(const float4*)(xrow + q * 8);
            float4 u1 = *(const float4*)(xrow + q * 8 + 4);
            float4 u2 = *(const float4*)(xrow + 32 + q * 8);
            float4 u3 = *(const float4*)(xrow + 32 + q * 8 + 4);
            f16x8 a0, a1;
            a0[0] = (_Float16)u0.x; a0[1] = (_Float16)u0.y; a0[2] = (_Float16)u0.z; a0[3] = (_Float16)u0.w;
            a0[4] = (_Float16)u1.x; a0[5] = (_Float16)u1.y; a0[6] = (_Float16)u1.z; a0[7] = (_Float16)u1.w;
            a1[0] = (_Float16)u2.x; a1[1] = (_Float16)u2.y; a1[2] = (_Float16)u2.z; a1[3] = (_Float16)u2.w;
            a1[4] = (_Float16)u3.x; a1[5] = (_Float16)u3.y; a1[6] = (_Float16)u3.z; a1[7] = (_Float16)u3.w;
            f32x4 ac0 = {0.f, 0.f, 0.f, 0.f}, ac1 = ac0, ac2 = ac0, ac3 = ac0;
            ac0 = __builtin_amdgcn_mfma_f32_16x16x32_f16(a0, bf[0][0], ac0, 0, 0, 0);
            ac1 = __builtin_amdgcn_mfma_f32_16x16x32_f16(a0, bf[1][0], ac1, 0, 0, 0);
            ac2 = __builtin_amdgcn_mfma_f32_16x16x32_f16(a0, bf[2][0], ac2, 0, 0, 0);
            ac3 = __builtin_amdgcn_mfma_f32_16x16x32_f16(a0, bf[3][0], ac3, 0, 0, 0);
            ac0 = __builtin_amdgcn_mfma_f32_16x16x32_f16(a1, bf[0][1], ac0, 0, 0, 0);
            ac1 = __builtin_amdgcn_mfma_f32_16x16x32_f16(a1, bf[1][1], ac1, 0, 0, 0);
            ac2 = __builtin_amdgcn_mfma_f32_16x16x32_f16(a1, bf[2][1], ac2, 0, 0, 0);
            ac3 = __builtin_amdgcn_mfma_f32_16x16x32_f16(a1, bf[3][1], ac3, 0, 0, 0);
#pragma unroll
            for (int reg = 0; reg < 4; ++reg) {
                int rl = t * 16 + q * 4 + reg;
                __half* dst = hp + (size_t)(n0 + rl) * 64 + mm;
                dst[0]  = __float2half(ac0[reg]);   // UNSCALED h
                dst[16] = __float2half(ac1[reg]);
                dst[32] = __float2half(ac2[reg]);
                dst[48] = __float2half(ac3[reg]);
            }
        }
    }
}

// ---- 2. per-bucket counting sort -> CSR (scol/offsets/deg/dinv) ------------
// One block per bucket (128 nodes). Wave0 shuffle scan (1 barrier).
__global__ __launch_bounds__(256, 4) void k_sort(const unsigned* __restrict__ pairbuf,
                                                 const int* __restrict__ relcur,
                                                 int* __restrict__ scol,
                                                 int* __restrict__ offsets,
                                                 int* __restrict__ deg,
                                                 float* __restrict__ dinv,
                                                 int N, int nb) {
    __shared__ int cnt[256];      // [128..255] stay 0
    __shared__ int spre[128];     // exclusive prefix
    __shared__ int cur[128];
    int b = blockIdx.x;
    int tid = threadIdx.x;
    int lo = b << CAPSH;
    int hi = lo + relcur[b];
    cnt[tid] = 0;
    __syncthreads();
    for (int i = lo + tid; i < hi; i += 256)
        atomicAdd(&cnt[pairbuf[i] >> 24], 1);      // values in [0,128)
    __syncthreads();
    // wave0: exclusive scan of 128 counts (2 chunks of 64)
    if (tid < 64) {
        int lane = tid, running = 0;
#pragma unroll
        for (int ch = 0; ch < 2; ++ch) {
            int idx = ch * 64 + lane;
            int v = cnt[idx];
            int s = v;
#pragma unroll
            for (int off = 1; off < 64; off <<= 1) {
                int t = __shfl_up(s, off, 64);
                if (lane >= off) s += t;
            }
            spre[idx] = running + s - v;
            running += __shfl(s, 63, 64);
        }
    }
    __syncthreads();
    int n0 = b << 7;
    if (tid < 128) {
        int cv = cnt[tid];
        int excl = spre[tid];
        int n = n0 + tid;
        if (n < N) {
            offsets[n] = lo + excl;
            deg[n] = cv;
            dinv[n] = rsqrtf((float)(cv + 1));     // +1 self-loop
        }
        cur[tid] = lo + excl;
    }
    if (b == 0 && tid == 0) {
        offsets[N] = 0; deg[N] = 0;                // clamped-node entry
        dinv[N] = 0.f;                             // sentinel scale -> 0 (never NaN)
        scol[nb << CAPSH] = N;                     // sentinel -> zero row
    }
    __syncthreads();
    for (int i = lo + tid; i < hi; i += 256) {
        unsigned it = pairbuf[i];
        int pos = atomicAdd(&cur[it >> 24], 1);
        scol[pos] = (int)(it & 0xFFFFFFu);
    }
}

// ---- 3. layer-1 agg (dinv at gather, fp32 accum) + relu(+b1) + W2 proj -----
// Wave = 8 nodes; slot=lane>>3 owns a node, chunk=lane&7 owns 16B of its row.
// 8-deep unrolled gathers; per-edge dinv[c] (L2-resident, lane-broadcast).
__global__ __launch_bounds__(256, 4) void k_agg1(const __half* __restrict__ hp,
                                                 const int* __restrict__ offsets,
                                                 const int* __restrict__ deg,
                                                 const int* __restrict__ scol,
                                                 const float* __restrict__ dinv,
                                                 const float* __restrict__ b1,
                                                 const float* __restrict__ W2,
                                                 float2* __restrict__ h2p,
                                                 int N, int SENT) {
    int lane = threadIdx.x & 63;
    int slot = lane >> 3;
    int chunk = lane & 7;
    int wid = (int)((blockIdx.x * 256 + threadIdx.x) >> 6);
    int n = wid * 8 + slot;
    int nc = (n < N) ? n : N;                 // row N of hp is the zero row
    int start = offsets[nc];
    int dg = deg[nc];                         // deg[N] = 0
    int maxd = dg;
#pragma unroll
    for (int s = 8; s <= 32; s <<= 1) {
        int o = __shfl_xor(maxd, s, 64);
        maxd = (o > maxd) ? o : maxd;
    }
    const float4* hp4 = (const float4*)hp;    // row stride = 8 float4
    float dn = dinv[(n < N) ? n : (N - 1)];
    float4 sr = hp4[(size_t)nc * 8 + chunk];  // self term (unscaled h)
    float af[8];
    {
        const __half2* hh = (const __half2*)&sr;
#pragma unroll
        for (int k = 0; k < 4; ++k) {
            float2 f = __half22float2(hh[k]);
            af[2 * k]     = dn * f.x;         // self contributes dinv_n * h_n
            af[2 * k + 1] = dn * f.y;
        }
    }
    for (int j0 = 0; j0 < maxd; j0 += 8) {
        int c[8];
#pragma unroll
        for (int u = 0; u < 8; ++u)
            c[u] = scol[(j0 + u < dg) ? (start + j0 + u) : SENT];  // SENT -> N
        float4 r[8];
#pragma unroll
        for (int u = 0; u < 8; ++u) r[u] = hp4[(size_t)c[u] * 8 + chunk];
        float dv[8];
#pragma unroll
        for (int u = 0; u < 8; ++u) dv[u] = dinv[c[u]];            // dinv[N]=0
#pragma unroll
        for (int u = 0; u < 8; ++u) {
            const __half2* hh = (const __half2*)&r[u];
#pragma unroll
            for (int k = 0; k < 4; ++k) {
                float2 f = __half22float2(hh[k]);
                af[2 * k]     = fmaf(dv[u], f.x, af[2 * k]);
                af[2 * k + 1] = fmaf(dv[u], f.y, af[2 * k + 1]);
            }
        }
    }
    float4 b1a = ((const float4*)b1)[chunk * 2];
    float4 b1b = ((const float4*)b1)[chunk * 2 + 1];
    float h1[8];
    h1[0] = fmaxf(fmaf(dn, af[0], b1a.x), 0.f);
    h1[1] = fmaxf(fmaf(dn, af[1], b1a.y), 0.f);
    h1[2] = fmaxf(fmaf(dn, af[2], b1a.z), 0.f);
    h1[3] = fmaxf(fmaf(dn, af[3], b1a.w), 0.f);
    h1[4] = fmaxf(fmaf(dn, af[4], b1b.x), 0.f);
    h1[5] = fmaxf(fmaf(dn, af[5], b1b.y), 0.f);
    h1[6] = fmaxf(fmaf(dn, af[6], b1b.z), 0.f);
    h1[7] = fmaxf(fmaf(dn, af[7], b1b.w), 0.f);
    float p0 = 0.f, p1 = 0.f;
#pragma unroll
    for (int k = 0; k < 4; ++k) {   // float4 = W2 rows {8c+2k, 8c+2k+1}
        float4 w = ((const float4*)W2)[chunk * 4 + k];
        p0 = fmaf(h1[2 * k], w.x, p0); p1 = fmaf(h1[2 * k], w.y, p1);
        p0 = fmaf(h1[2 * k + 1], w.z, p0); p1 = fmaf(h1[2 * k + 1], w.w, p1);
    }
#pragma unroll
    for (int s = 1; s <= 4; s <<= 1) {  // reduce across chunk (bits 0,1,2)
        p0 += __shfl_xor(p0, s, 64);
        p1 += __shfl_xor(p1, s, 64);
    }
    if (chunk == 0 && n < N) h2p[n] = make_float2(dn * p0, dn * p1);  // pre-scaled
}

// ---- 4. layer-2 agg + softmax: 16 lanes per node ---------------------------
__global__ __launch_bounds__(256) void k_agg2(const float2* __restrict__ h2p,
                                              const int* __restrict__ offsets,
                                              const int* __restrict__ deg,
                                              const int* __restrict__ scol,
                                              const float* __restrict__ dinv,
                                              const float* __restrict__ b2,
                                              float2* __restrict__ out, int N) {
    int gtid = blockIdx.x * 256 + threadIdx.x;
    int n = gtid >> 4;
    int sub = threadIdx.x & 15;
    if (n >= N) return;
    int start = offsets[n], end = start + deg[n];
    float ax = 0.f, ay = 0.f;
    if (sub == 0) { float2 s = h2p[n]; ax = s.x; ay = s.y; }   // self (pre-scaled)
    for (int j = start + sub; j < end; j += 16) {
        float2 v = h2p[scol[j]];
        ax += v.x; ay += v.y;
    }
#pragma unroll
    for (int s = 1; s <= 8; s <<= 1) {
        ax += __shfl_xor(ax, s, 64);
        ay += __shfl_xor(ay, s, 64);
    }
    if (sub == 0) {
        float dn = dinv[n];
        float l0 = fmaf(dn, ax, b2[0]), l1 = fmaf(dn, ay, b2[1]);
        float m = fmaxf(l0, l1);
        float e0 = __expf(l0 - m), e1 = __expf(l1 - m);
        float inv = 1.0f / (e0 + e1);
        out[n] = make_float2(e0 * inv, e1 * inv);
    }
}

extern "C" void kernel_launch(void* const* d_in, const int* in_sizes, int n_in,
                              void* d_out, int out_size, void* d_ws, size_t ws_size,
                              hipStream_t stream) {
    const float* x  = (const float*)d_in[0];
    const int*   ei = (const int*)d_in[1];
    const float* W1 = (const float*)d_in[2];
    const float* b1 = (const float*)d_in[3];
    const float* W2 = (const float*)d_in[4];
    const float* b2 = (const float*)d_in[5];
    float2* out = (float2*)d_out;

    const int N = in_sizes[0] / 64;     // 100000 (N%16==0, N<2^24)
    const int E = in_sizes[1] / 2;      // 1600000
    const int nb = (N + 127) >> 7;      // 782 buckets of 128 nodes
    const int SENT = nb << CAPSH;
    const int* row = ei;
    const int* col = ei + E;

    char* p = (char*)d_ws;
    auto alloc = [&](size_t bytes) -> void* {
        void* r = (void*)p;
        p += (bytes + 255) & ~(size_t)255;
        return r;
    };
    int*   relcur  = (int*)alloc((size_t)nb * 4);               // memset exact (R4 lesson)
    int*   offsets = (int*)alloc((size_t)(N + 1) * 4);
    int*   deg     = (int*)alloc((size_t)(N + 1) * 4);
    float* dinv    = (float*)alloc((size_t)(N + 1) * 4);        // +1: dinv[N]=0 sentinel
    unsigned* pairbuf = (unsigned*)alloc((size_t)nb * CAP * 4);
    int*   scol    = (int*)alloc(((size_t)nb * CAP + 1) * 4);   // +1 sentinel
    __half* hp     = (__half*)alloc((size_t)(N + 1) * 64 * 2);  // +1 zero row
    float2* h2p    = (float2*)alloc((size_t)N * 8);

    const int nTileB = (E + 4095) / 4096;   // 391 bin blocks
    const int nGemm  = (N + 255) >> 8;      // 391 gemm blocks (256 nodes each)

    hipMemsetAsync(relcur, 0, (size_t)nb * 4, stream);
    k_binfused<<<nTileB + nGemm, 256, 0, stream>>>(row, col, relcur, pairbuf, hp,
                                                   x, W1, E, nb, N, nTileB);
    k_sort<<<nb, 256, 0, stream>>>(pairbuf, relcur, scol, offsets, deg, dinv, N, nb);
    const int nwaves = (N + 7) / 8;                  // 8 nodes per wave
    k_agg1<<<(nwaves + 3) / 4, 256, 0, stream>>>(hp, offsets, deg, scol, dinv, b1, W2, h2p, N, SENT);
    k_agg2<<<(N * 16 + 255) / 256, 256, 0, stream>>>(h2p, offsets, deg, scol, dinv, b2, out, N);
}

// Round 3
// 161.895 us; speedup vs baseline: 1.0479x; 1.0239x over previous
//
#include <hip/hip_runtime.h>
#include <hip/hip_fp16.h>

// GCN 2-layer forward: out = softmax( A_norm @ relu(A_norm @ (x@W1) + b1) @ W2 + b2 )
// A_norm = D^-1/2 (A + I) D^-1/2, edges are col->row (row = target).
//
// R15 -> R16: FP8 HIDDEN ROWS. R15 showed intermediates are L3-resident
// (FETCH_SIZE ~ 0 on fills) => the cost is L3 random lines, not HBM bytes.
// agg1 gathers 1.6M rows; at fp16 a row = 128 B = 2 lines (205 MB random L3).
// Store h as OCP e4m3 fp8: row = 64 B = ONE line per edge — halves both L3
// random bytes and TCP line requests. Unpack via v_cvt_pk_f32_fp8 (same VALU
// count as the old half2 path); accumulate stays fp32 with dinv at gather.
// Everything else identical to R15 for a clean A/B.
// 5 dispatches: memset(relcur) -> bin+gemm -> sort -> agg1 -> agg2.

typedef _Float16 f16x8 __attribute__((ext_vector_type(8)));
typedef float f32x4 __attribute__((ext_vector_type(4)));
typedef float f32x2 __attribute__((ext_vector_type(2)));

#define CAPSH 12
#define CAP (1 << CAPSH)          // per-bucket pairbuf/scol capacity
#define NBK 784                   // LDS array size (>= nb = 782)

__device__ __forceinline__ unsigned char pack_fp8(float v) {
    return (unsigned char)(__builtin_amdgcn_cvt_pk_fp8_f32(v, 0.f, 0, false) & 0xFF);
}

__device__ __forceinline__ void unpack8_fp8(uint2 w, float* f) {
    f32x2 a = __builtin_amdgcn_cvt_pk_f32_fp8(w.x, false);
    f32x2 b = __builtin_amdgcn_cvt_pk_f32_fp8(w.x, true);
    f32x2 c = __builtin_amdgcn_cvt_pk_f32_fp8(w.y, false);
    f32x2 d = __builtin_amdgcn_cvt_pk_f32_fp8(w.y, true);
    f[0] = a.x; f[1] = a.y; f[2] = b.x; f[3] = b.y;
    f[4] = c.x; f[5] = c.y; f[6] = d.x; f[7] = d.y;
}

// ---- 1. fused: bin edges into per-bucket slices  |  gemm hp8 = fp8(x@W1) ---
// blocks [0, nTileB): bin role (4096-edge tiles).
// blocks [nTileB, nTileB+nGemm): gemm role, 256 nodes/block, unscaled fp8 out.
__global__ __launch_bounds__(256, 4) void k_binfused(const int* __restrict__ row,
                                                     const int* __restrict__ col,
                                                     int* __restrict__ relcur,
                                                     unsigned* __restrict__ pairbuf,
                                                     unsigned char* __restrict__ hp8,
                                                     const float* __restrict__ x,
                                                     const float* __restrict__ W1,
                                                     int E, int nb, int N, int nTileB) {
    __shared__ unsigned items[4096];        // (r&127)<<24 | col
    __shared__ unsigned short bktid[4096];
    __shared__ int cnt[NBK];
    __shared__ int start0[NBK];
    __shared__ int cursor[NBK];
    __shared__ int gbase[NBK];

    int tid = threadIdx.x;

    if (blockIdx.x < nTileB) {
        // ------------------------- bin role -------------------------
        int base = blockIdx.x * 4096;
        int m = E - base; if (m > 4096) m = 4096;

        for (int t = tid; t < nb; t += 256) cnt[t] = 0;
        __syncthreads();
        for (int i = tid; i < m; i += 256) atomicAdd(&cnt[row[base + i] >> 7], 1);
        __syncthreads();
        // wave0: exclusive scan of tile counts -> start0, cursor (13 chunks of 64)
        if (tid < 64) {
            int lane = tid, running = 0;
            for (int ch = 0; ch < 13; ++ch) {
                int idx = ch * 64 + lane;
                int v = (idx < nb) ? cnt[idx] : 0;
                int s = v;
#pragma unroll
                for (int off = 1; off < 64; off <<= 1) {
                    int t = __shfl_up(s, off, 64);
                    if (lane >= off) s += t;
                }
                if (idx < nb) { start0[idx] = running + s - v; cursor[idx] = running + s - v; }
                running += __shfl(s, 63, 64);
            }
        }
        __syncthreads();
        for (int i = tid; i < m; i += 256) {
            int r = row[base + i];
            int c = col[base + i];
            int b = r >> 7;
            int pos = atomicAdd(&cursor[b], 1);
            items[pos] = ((unsigned)(r & 127) << 24) | (unsigned)c;
            bktid[pos] = (unsigned short)b;
        }
        __syncthreads();
        // claim global space: bucket b's slice starts at b*CAP
        for (int t = tid; t < nb; t += 256) {
            int cv = cnt[t];
            if (cv > 0) gbase[t] = (t << CAPSH) + atomicAdd(&relcur[t], cv);
        }
        __syncthreads();
        for (int i = tid; i < m; i += 256) {
            int b = bktid[i];
            pairbuf[gbase[b] + (i - start0[b])] = items[i];
        }
        if (blockIdx.x == 0 && tid < 16) ((int*)(hp8 + (size_t)N * 64))[tid] = 0;  // zero row (64B)
    } else {
        // ------------------------- gemm role ------------------------
        int g = blockIdx.x - nTileB;
        int n0 = g << 8;                       // 256 nodes per gemm block
        int lane = tid & 63, q = lane >> 4, mm = lane & 15;
        // B-frags (W1 fp16): B[k][n], n=nt*16+mm, k=kk*32+q*8+j
        f16x8 bf[4][2];
#pragma unroll
        for (int nt = 0; nt < 4; ++nt)
#pragma unroll
            for (int kk = 0; kk < 2; ++kk)
#pragma unroll
                for (int j = 0; j < 8; ++j)
                    bf[nt][kk][j] = (_Float16)W1[(kk * 32 + q * 8 + j) * 64 + nt * 16 + mm];

        int nn = N - n0; if (nn > 256) nn = 256;   // N%16==0 -> whole tiles
        for (int t = (tid >> 6); t < (nn >> 4); t += 4) {
            const float* xrow = x + (size_t)(n0 + t * 16 + mm) * 64;
            float4 u0 = *(const float4*)(xrow + q * 8);
            float4 u1 = *(const float4*)(xrow + q * 8 + 4);
            float4 u2 = *(const float4*)(xrow + 32 + q * 8);
            float4 u3 = *(const float4*)(xrow + 32 + q * 8 + 4);
            f16x8 a0, a1;
            a0[0] = (_Float16)u0.x; a0[1] = (_Float16)u0.y; a0[2] = (_Float16)u0.z; a0[3] = (_Float16)u0.w;
            a0[4] = (_Float16)u1.x; a0[5] = (_Float16)u1.y; a0[6] = (_Float16)u1.z; a0[7] = (_Float16)u1.w;
            a1[0] = (_Float16)u2.x; a1[1] = (_Float16)u2.y; a1[2] = (_Float16)u2.z; a1[3] = (_Float16)u2.w;
            a1[4] = (_Float16)u3.x; a1[5] = (_Float16)u3.y; a1[6] = (_Float16)u3.z; a1[7] = (_Float16)u3.w;
            f32x4 ac0 = {0.f, 0.f, 0.f, 0.f}, ac1 = ac0, ac2 = ac0, ac3 = ac0;
            ac0 = __builtin_amdgcn_mfma_f32_16x16x32_f16(a0, bf[0][0], ac0, 0, 0, 0);
            ac1 = __builtin_amdgcn_mfma_f32_16x16x32_f16(a0, bf[1][0], ac1, 0, 0, 0);
            ac2 = __builtin_amdgcn_mfma_f32_16x16x32_f16(a0, bf[2][0], ac2, 0, 0, 0);
            ac3 = __builtin_amdgcn_mfma_f32_16x16x32_f16(a0, bf[3][0], ac3, 0, 0, 0);
            ac0 = __builtin_amdgcn_mfma_f32_16x16x32_f16(a1, bf[0][1], ac0, 0, 0, 0);
            ac1 = __builtin_amdgcn_mfma_f32_16x16x32_f16(a1, bf[1][1], ac1, 0, 0, 0);
            ac2 = __builtin_amdgcn_mfma_f32_16x16x32_f16(a1, bf[2][1], ac2, 0, 0, 0);
            ac3 = __builtin_amdgcn_mfma_f32_16x16x32_f16(a1, bf[3][1], ac3, 0, 0, 0);
#pragma unroll
            for (int reg = 0; reg < 4; ++reg) {
                int rl = t * 16 + q * 4 + reg;
                unsigned char* dst = hp8 + (size_t)(n0 + rl) * 64 + mm;
                dst[0]  = pack_fp8(ac0[reg]);   // UNSCALED h, e4m3
                dst[16] = pack_fp8(ac1[reg]);
                dst[32] = pack_fp8(ac2[reg]);
                dst[48] = pack_fp8(ac3[reg]);
            }
        }
    }
}

// ---- 2. per-bucket counting sort -> CSR (scol/offsets/deg/dinv) ------------
// One block per bucket (128 nodes). Wave0 shuffle scan (1 barrier).
__global__ __launch_bounds__(256, 4) void k_sort(const unsigned* __restrict__ pairbuf,
                                                 const int* __restrict__ relcur,
                                                 int* __restrict__ scol,
                                                 int* __restrict__ offsets,
                                                 int* __restrict__ deg,
                                                 float* __restrict__ dinv,
                                                 int N, int nb) {
    __shared__ int cnt[256];      // [128..255] stay 0
    __shared__ int spre[128];     // exclusive prefix
    __shared__ int cur[128];
    int b = blockIdx.x;
    int tid = threadIdx.x;
    int lo = b << CAPSH;
    int hi = lo + relcur[b];
    cnt[tid] = 0;
    __syncthreads();
    for (int i = lo + tid; i < hi; i += 256)
        atomicAdd(&cnt[pairbuf[i] >> 24], 1);      // values in [0,128)
    __syncthreads();
    // wave0: exclusive scan of 128 counts (2 chunks of 64)
    if (tid < 64) {
        int lane = tid, running = 0;
#pragma unroll
        for (int ch = 0; ch < 2; ++ch) {
            int idx = ch * 64 + lane;
            int v = cnt[idx];
            int s = v;
#pragma unroll
            for (int off = 1; off < 64; off <<= 1) {
                int t = __shfl_up(s, off, 64);
                if (lane >= off) s += t;
            }
            spre[idx] = running + s - v;
            running += __shfl(s, 63, 64);
        }
    }
    __syncthreads();
    int n0 = b << 7;
    if (tid < 128) {
        int cv = cnt[tid];
        int excl = spre[tid];
        int n = n0 + tid;
        if (n < N) {
            offsets[n] = lo + excl;
            deg[n] = cv;
            dinv[n] = rsqrtf((float)(cv + 1));     // +1 self-loop
        }
        cur[tid] = lo + excl;
    }
    if (b == 0 && tid == 0) {
        offsets[N] = 0; deg[N] = 0;                // clamped-node entry
        dinv[N] = 0.f;                             // sentinel scale -> 0 (never NaN)
        scol[nb << CAPSH] = N;                     // sentinel -> zero row
    }
    __syncthreads();
    for (int i = lo + tid; i < hi; i += 256) {
        unsigned it = pairbuf[i];
        int pos = atomicAdd(&cur[it >> 24], 1);
        scol[pos] = (int)(it & 0xFFFFFFu);
    }
}

// ---- 3. layer-1 agg (fp8 gather, dinv at gather, fp32 accum) + b1/relu/W2 --
// Wave = 8 nodes; slot=lane>>3 owns a node, chunk=lane&7 owns 8B of its row.
// 8-deep unrolled gathers; each edge's row = ONE 64B line.
__global__ __launch_bounds__(256, 4) void k_agg1(const unsigned char* __restrict__ hp8,
                                                 const int* __restrict__ offsets,
                                                 const int* __restrict__ deg,
                                                 const int* __restrict__ scol,
                                                 const float* __restrict__ dinv,
                                                 const float* __restrict__ b1,
                                                 const float* __restrict__ W2,
                                                 float2* __restrict__ h2p,
                                                 int N, int SENT) {
    int lane = threadIdx.x & 63;
    int slot = lane >> 3;
    int chunk = lane & 7;
    int wid = (int)((blockIdx.x * 256 + threadIdx.x) >> 6);
    int n = wid * 8 + slot;
    int nc = (n < N) ? n : N;                 // row N of hp8 is the zero row
    int start = offsets[nc];
    int dg = deg[nc];                         // deg[N] = 0
    int maxd = dg;
#pragma unroll
    for (int s = 8; s <= 32; s <<= 1) {
        int o = __shfl_xor(maxd, s, 64);
        maxd = (o > maxd) ? o : maxd;
    }
    const uint2* hp2 = (const uint2*)hp8;     // row stride = 8 uint2 (64 B)
    float dn = dinv[(n < N) ? n : (N - 1)];
    float af[8];
    {
        uint2 sr = hp2[(size_t)nc * 8 + chunk];   // self term (unscaled h)
        float fs[8];
        unpack8_fp8(sr, fs);
#pragma unroll
        for (int k = 0; k < 8; ++k) af[k] = dn * fs[k];
    }
    for (int j0 = 0; j0 < maxd; j0 += 8) {
        int c[8];
#pragma unroll
        for (int u = 0; u < 8; ++u)
            c[u] = scol[(j0 + u < dg) ? (start + j0 + u) : SENT];  // SENT -> N
        uint2 r[8];
#pragma unroll
        for (int u = 0; u < 8; ++u) r[u] = hp2[(size_t)c[u] * 8 + chunk];
        float dv[8];
#pragma unroll
        for (int u = 0; u < 8; ++u) dv[u] = dinv[c[u]];            // dinv[N]=0
#pragma unroll
        for (int u = 0; u < 8; ++u) {
            float f[8];
            unpack8_fp8(r[u], f);
#pragma unroll
            for (int k = 0; k < 8; ++k)
                af[k] = fmaf(dv[u], f[k], af[k]);
        }
    }
    float4 b1a = ((const float4*)b1)[chunk * 2];
    float4 b1b = ((const float4*)b1)[chunk * 2 + 1];
    float h1[8];
    h1[0] = fmaxf(fmaf(dn, af[0], b1a.x), 0.f);
    h1[1] = fmaxf(fmaf(dn, af[1], b1a.y), 0.f);
    h1[2] = fmaxf(fmaf(dn, af[2], b1a.z), 0.f);
    h1[3] = fmaxf(fmaf(dn, af[3], b1a.w), 0.f);
    h1[4] = fmaxf(fmaf(dn, af[4], b1b.x), 0.f);
    h1[5] = fmaxf(fmaf(dn, af[5], b1b.y), 0.f);
    h1[6] = fmaxf(fmaf(dn, af[6], b1b.z), 0.f);
    h1[7] = fmaxf(fmaf(dn, af[7], b1b.w), 0.f);
    float p0 = 0.f, p1 = 0.f;
#pragma unroll
    for (int k = 0; k < 4; ++k) {   // float4 = W2 rows {8c+2k, 8c+2k+1}
        float4 w = ((const float4*)W2)[chunk * 4 + k];
        p0 = fmaf(h1[2 * k], w.x, p0); p1 = fmaf(h1[2 * k], w.y, p1);
        p0 = fmaf(h1[2 * k + 1], w.z, p0); p1 = fmaf(h1[2 * k + 1], w.w, p1);
    }
#pragma unroll
    for (int s = 1; s <= 4; s <<= 1) {  // reduce across chunk (bits 0,1,2)
        p0 += __shfl_xor(p0, s, 64);
        p1 += __shfl_xor(p1, s, 64);
    }
    if (chunk == 0 && n < N) h2p[n] = make_float2(dn * p0, dn * p1);  // pre-scaled
}

// ---- 4. layer-2 agg + softmax: 16 lanes per node ---------------------------
__global__ __launch_bounds__(256) void k_agg2(const float2* __restrict__ h2p,
                                              const int* __restrict__ offsets,
                                              const int* __restrict__ deg,
                                              const int* __restrict__ scol,
                                              const float* __restrict__ dinv,
                                              const float* __restrict__ b2,
                                              float2* __restrict__ out, int N) {
    int gtid = blockIdx.x * 256 + threadIdx.x;
    int n = gtid >> 4;
    int sub = threadIdx.x & 15;
    if (n >= N) return;
    int start = offsets[n], end = start + deg[n];
    float ax = 0.f, ay = 0.f;
    if (sub == 0) { float2 s = h2p[n]; ax = s.x; ay = s.y; }   // self (pre-scaled)
    for (int j = start + sub; j < end; j += 16) {
        float2 v = h2p[scol[j]];
        ax += v.x; ay += v.y;
    }
#pragma unroll
    for (int s = 1; s <= 8; s <<= 1) {
        ax += __shfl_xor(ax, s, 64);
        ay += __shfl_xor(ay, s, 64);
    }
    if (sub == 0) {
        float dn = dinv[n];
        float l0 = fmaf(dn, ax, b2[0]), l1 = fmaf(dn, ay, b2[1]);
        float m = fmaxf(l0, l1);
        float e0 = __expf(l0 - m), e1 = __expf(l1 - m);
        float inv = 1.0f / (e0 + e1);
        out[n] = make_float2(e0 * inv, e1 * inv);
    }
}

extern "C" void kernel_launch(void* const* d_in, const int* in_sizes, int n_in,
                              void* d_out, int out_size, void* d_ws, size_t ws_size,
                              hipStream_t stream) {
    const float* x  = (const float*)d_in[0];
    const int*   ei = (const int*)d_in[1];
    const float* W1 = (const float*)d_in[2];
    const float* b1 = (const float*)d_in[3];
    const float* W2 = (const float*)d_in[4];
    const float* b2 = (const float*)d_in[5];
    float2* out = (float2*)d_out;

    const int N = in_sizes[0] / 64;     // 100000 (N%16==0, N<2^24)
    const int E = in_sizes[1] / 2;      // 1600000
    const int nb = (N + 127) >> 7;      // 782 buckets of 128 nodes
    const int SENT = nb << CAPSH;
    const int* row = ei;
    const int* col = ei + E;

    char* p = (char*)d_ws;
    auto alloc = [&](size_t bytes) -> void* {
        void* r = (void*)p;
        p += (bytes + 255) & ~(size_t)255;
        return r;
    };
    int*   relcur  = (int*)alloc((size_t)nb * 4);               // memset exact (R4 lesson)
    int*   offsets = (int*)alloc((size_t)(N + 1) * 4);
    int*   deg     = (int*)alloc((size_t)(N + 1) * 4);
    float* dinv    = (float*)alloc((size_t)(N + 1) * 4);        // +1: dinv[N]=0 sentinel
    unsigned* pairbuf = (unsigned*)alloc((size_t)nb * CAP * 4);
    int*   scol    = (int*)alloc(((size_t)nb * CAP + 1) * 4);   // +1 sentinel
    unsigned char* hp8 = (unsigned char*)alloc((size_t)(N + 1) * 64);  // fp8 rows, +1 zero row
    float2* h2p    = (float2*)alloc((size_t)N * 8);

    const int nTileB = (E + 4095) / 4096;   // 391 bin blocks
    const int nGemm  = (N + 255) >> 8;      // 391 gemm blocks (256 nodes each)

    hipMemsetAsync(relcur, 0, (size_t)nb * 4, stream);
    k_binfused<<<nTileB + nGemm, 256, 0, stream>>>(row, col, relcur, pairbuf, hp8,
                                                   x, W1, E, nb, N, nTileB);
    k_sort<<<nb, 256, 0, stream>>>(pairbuf, relcur, scol, offsets, deg, dinv, N, nb);
    const int nwaves = (N + 7) / 8;                  // 8 nodes per wave
    k_agg1<<<(nwaves + 3) / 4, 256, 0, stream>>>(hp8, offsets, deg, scol, dinv, b1, W2, h2p, N, SENT);
    k_agg2<<<(N * 16 + 255) / 256, 256, 0, stream>>>(h2p, offsets, deg, scol, dinv, b2, out, N);
}